// Round 1
// baseline (985.808 us; speedup 1.0000x reference)
//
#include <hip/hip_runtime.h>

namespace {
constexpr int Wd = 960;
constexpr int Hd = 544;
constexpr int Cd = 16;
constexpr int Id = 5;
constexpr int Bd = 2;
constexpr int HW = Hd * Wd;                       // 522240
constexpr long CHW = (long)Cd * HW;               // 8,355,840
constexpr long FRAME_BSTRIDE = (long)Id * CHW;    // batch stride in features/out
constexpr long FLOW_BSTRIDE  = (long)Id * 2 * HW; // batch stride in mv
}

// Backward bilinear warp with zeros padding, one frame (all B batches, all C
// channels). src/dst are pre-offset to the frame; batch stride applied inside.
__global__ __launch_bounds__(256) void warp_kernel(
    const float* __restrict__ src, float* __restrict__ dst,
    const float* __restrict__ flow)
{
  int tid = blockIdx.x * blockDim.x + threadIdx.x;
  if (tid >= Bd * HW) return;
  int b   = tid / HW;
  int pix = tid - b * HW;
  int y = pix / Wd;
  int x = pix - y * Wd;

  const float* fl = flow + (long)b * FLOW_BSTRIDE;
  float fx = fl[pix];
  float fy = fl[HW + pix];

  float gx = (float)x + fx;
  float gy = (float)y + fy;
  float x0f = floorf(gx);
  float y0f = floorf(gy);
  float wx = gx - x0f;
  float wy = gy - y0f;
  float x1f = x0f + 1.0f;
  float y1f = y0f + 1.0f;

  bool vx0 = (x0f >= 0.0f) && (x0f <= (float)(Wd - 1));
  bool vx1 = (x1f >= 0.0f) && (x1f <= (float)(Wd - 1));
  bool vy0 = (y0f >= 0.0f) && (y0f <= (float)(Hd - 1));
  bool vy1 = (y1f >= 0.0f) && (y1f <= (float)(Hd - 1));

  int xc0 = (int)fminf(fmaxf(x0f, 0.0f), (float)(Wd - 1));
  int xc1 = (int)fminf(fmaxf(x1f, 0.0f), (float)(Wd - 1));
  int yc0 = (int)fminf(fmaxf(y0f, 0.0f), (float)(Hd - 1));
  int yc1 = (int)fminf(fmaxf(y1f, 0.0f), (float)(Hd - 1));

  float w00 = (1.0f - wx) * (1.0f - wy) * ((vx0 && vy0) ? 1.0f : 0.0f);
  float w10 = wx * (1.0f - wy)          * ((vx1 && vy0) ? 1.0f : 0.0f);
  float w01 = (1.0f - wx) * wy          * ((vx0 && vy1) ? 1.0f : 0.0f);
  float w11 = wx * wy                   * ((vx1 && vy1) ? 1.0f : 0.0f);

  int i00 = yc0 * Wd + xc0;
  int i10 = yc0 * Wd + xc1;
  int i01 = yc1 * Wd + xc0;
  int i11 = yc1 * Wd + xc1;

  const float* s = src + (long)b * FRAME_BSTRIDE;
  float*       d = dst + (long)b * FRAME_BSTRIDE;
#pragma unroll
  for (int c = 0; c < Cd; ++c) {
    const float* sp = s + (long)c * HW;
    float v = w00 * sp[i00] + w10 * sp[i10] + w01 * sp[i01] + w11 * sp[i11];
    d[(long)c * HW + pix] = v;
  }
}

extern "C" void kernel_launch(void* const* d_in, const int* in_sizes, int n_in,
                              void* d_out, int out_size, void* d_ws, size_t ws_size,
                              hipStream_t stream) {
  const float* feat = (const float*)d_in[0];
  const float* mv   = (const float*)d_in[1];
  float*       out  = (float*)d_out;

  const int grid = (Bd * HW + 255) / 256;

  // Scratch = frame-0 slot of d_out (frame 0 is written last, by plain copy).
  float* S = out;  // per batch b: out + b*FRAME_BSTRIDE + 0*CHW

  auto warp = [&](const float* src, float* dst, int j) {
    warp_kernel<<<grid, 256, 0, stream>>>(src, dst, mv + (long)j * 2 * HW);
  };

  // frame 1: mv0
  warp(feat + 1 * CHW, out + 1 * CHW, 0);
  // frame 2: mv1, mv0  (even chain: start in scratch)
  warp(feat + 2 * CHW, S, 1);
  warp(S, out + 2 * CHW, 0);
  // frame 3: mv2, mv1, mv0  (odd chain: start in own slot)
  warp(feat + 3 * CHW, out + 3 * CHW, 2);
  warp(out + 3 * CHW, S, 1);
  warp(S, out + 3 * CHW, 0);
  // frame 4: mv3, mv2, mv1, mv0  (even chain)
  warp(feat + 4 * CHW, S, 3);
  warp(S, out + 4 * CHW, 2);
  warp(out + 4 * CHW, S, 1);
  warp(S, out + 4 * CHW, 0);

  // frame 0: plain copy (after all scratch uses of the frame-0 slot).
  for (int b = 0; b < Bd; ++b) {
    hipMemcpyAsync(out + (long)b * FRAME_BSTRIDE,
                   feat + (long)b * FRAME_BSTRIDE,
                   CHW * sizeof(float), hipMemcpyDeviceToDevice, stream);
  }
}

// Round 2
// 930.750 us; speedup vs baseline: 1.0592x; 1.0592x over previous
//
#include <hip/hip_runtime.h>

namespace {
constexpr int Wd = 960;
constexpr int Hd = 544;
constexpr int Cd = 16;
constexpr int Id = 5;
constexpr int Bd = 2;
constexpr int HW = Hd * Wd;                       // 522240
constexpr long CHW = (long)Cd * HW;               // 8,355,840
constexpr long FRAME_BSTRIDE = (long)Id * CHW;    // batch stride in features/out
constexpr long FLOW_BSTRIDE  = (long)Id * 2 * HW; // batch stride in mv
}

// Backward bilinear warp, zeros padding, one frame (all B, all C).
// Block = 16x16 threads; each wave covers a 16x4 pixel patch (compact gather
// footprint). Interior-x pixels use paired float2 corner loads.
__global__ __launch_bounds__(256) void warp_kernel(
    const float* __restrict__ src, float* __restrict__ dst,
    const float* __restrict__ flow)
{
  int x = blockIdx.x * 16 + threadIdx.x;
  int y = blockIdx.y * 16 + threadIdx.y;
  int b = blockIdx.z;
  int pix = y * Wd + x;

  const float* fl = flow + (long)b * FLOW_BSTRIDE;
  float fx = fl[pix];
  float fy = fl[HW + pix];

  float gx = (float)x + fx;
  float gy = (float)y + fy;
  float x0f = floorf(gx);
  float y0f = floorf(gy);
  float wx = gx - x0f;
  float wy = gy - y0f;

  bool vy0 = (y0f >= 0.0f) && (y0f <= (float)(Hd - 1));
  bool vy1 = (y0f + 1.0f >= 0.0f) && (y0f + 1.0f <= (float)(Hd - 1));
  int yc0 = (int)fminf(fmaxf(y0f, 0.0f), (float)(Hd - 1));
  int yc1 = (int)fminf(fmaxf(y0f + 1.0f, 0.0f), (float)(Hd - 1));
  float my0 = vy0 ? 1.0f : 0.0f;
  float my1 = vy1 ? 1.0f : 0.0f;

  const float* s = src + (long)b * FRAME_BSTRIDE;
  float*       d = dst + (long)b * FRAME_BSTRIDE;

  if (x0f >= 0.0f && x0f <= (float)(Wd - 2)) {
    // Interior in x: both columns valid, paired 8B corner loads.
    int xi = (int)x0f;
    float a00 = (1.0f - wx) * (1.0f - wy) * my0;
    float a10 = wx * (1.0f - wy) * my0;
    float a01 = (1.0f - wx) * wy * my1;
    float a11 = wx * wy * my1;
    long o0 = (long)yc0 * Wd + xi;
    long o1 = (long)yc1 * Wd + xi;
#pragma unroll
    for (int c = 0; c < Cd; ++c) {
      const float* sp = s + (long)c * HW;
      float2 r0 = *reinterpret_cast<const float2*>(sp + o0);
      float2 r1 = *reinterpret_cast<const float2*>(sp + o1);
      d[(long)c * HW + pix] = a00 * r0.x + a10 * r0.y + a01 * r1.x + a11 * r1.y;
    }
  } else {
    // Edge in x: scalar clamped path with per-corner masks.
    float x1f = x0f + 1.0f;
    bool vx0 = (x0f >= 0.0f) && (x0f <= (float)(Wd - 1));
    bool vx1 = (x1f >= 0.0f) && (x1f <= (float)(Wd - 1));
    int xc0 = (int)fminf(fmaxf(x0f, 0.0f), (float)(Wd - 1));
    int xc1 = (int)fminf(fmaxf(x1f, 0.0f), (float)(Wd - 1));
    float w00 = (1.0f - wx) * (1.0f - wy) * (vx0 ? my0 : 0.0f);
    float w10 = wx * (1.0f - wy) * (vx1 ? my0 : 0.0f);
    float w01 = (1.0f - wx) * wy * (vx0 ? my1 : 0.0f);
    float w11 = wx * wy * (vx1 ? my1 : 0.0f);
    long i00 = (long)yc0 * Wd + xc0;
    long i10 = (long)yc0 * Wd + xc1;
    long i01 = (long)yc1 * Wd + xc0;
    long i11 = (long)yc1 * Wd + xc1;
#pragma unroll
    for (int c = 0; c < Cd; ++c) {
      const float* sp = s + (long)c * HW;
      float v = w00 * sp[i00] + w10 * sp[i10] + w01 * sp[i01] + w11 * sp[i11];
      d[(long)c * HW + pix] = v;
    }
  }
}

extern "C" void kernel_launch(void* const* d_in, const int* in_sizes, int n_in,
                              void* d_out, int out_size, void* d_ws, size_t ws_size,
                              hipStream_t stream) {
  const float* feat = (const float*)d_in[0];
  const float* mv   = (const float*)d_in[1];
  float*       out  = (float*)d_out;

  dim3 block(16, 16, 1);
  dim3 grid(Wd / 16, Hd / 16, Bd);  // 60 x 34 x 2

  // Scratch = frame-0 slot of d_out (frame 0 is written last, by plain copy).
  float* S = out;

  auto warp = [&](const float* src, float* dst, int j) {
    warp_kernel<<<grid, block, 0, stream>>>(src, dst, mv + (long)j * 2 * HW);
  };

  // frame 1: mv0
  warp(feat + 1 * CHW, out + 1 * CHW, 0);
  // frame 2: mv1, mv0  (even chain: start in scratch)
  warp(feat + 2 * CHW, S, 1);
  warp(S, out + 2 * CHW, 0);
  // frame 3: mv2, mv1, mv0  (odd chain: start in own slot)
  warp(feat + 3 * CHW, out + 3 * CHW, 2);
  warp(out + 3 * CHW, S, 1);
  warp(S, out + 3 * CHW, 0);
  // frame 4: mv3, mv2, mv1, mv0  (even chain)
  warp(feat + 4 * CHW, S, 3);
  warp(S, out + 4 * CHW, 2);
  warp(out + 4 * CHW, S, 1);
  warp(S, out + 4 * CHW, 0);

  // frame 0: plain copy (after all scratch uses of the frame-0 slot).
  for (int b = 0; b < Bd; ++b) {
    hipMemcpyAsync(out + (long)b * FRAME_BSTRIDE,
                   feat + (long)b * FRAME_BSTRIDE,
                   CHW * sizeof(float), hipMemcpyDeviceToDevice, stream);
  }
}

// Round 3
// 608.437 us; speedup vs baseline: 1.6202x; 1.5297x over previous
//
#include <hip/hip_runtime.h>
#include <stdint.h>

namespace {
constexpr int Wd = 960;
constexpr int Hd = 544;
constexpr int Cd = 16;
constexpr int Id = 5;
constexpr int Bd = 2;
constexpr int HW = Hd * Wd;                       // 522240
constexpr long CHW = (long)Cd * HW;               // 8,355,840
constexpr long FRAME_BSTRIDE = (long)Id * CHW;    // batch stride in features/out
constexpr long FLOW_BSTRIDE  = (long)Id * 2 * HW; // batch stride in mv
constexpr int TS   = 32;   // output tile (32x32 px per block)
constexpr int HALO = 16;   // sample halo (4 sigma of the 4px flow)
constexpr int TW   = 64;   // staged tile span = TS + 2*HALO
}

// Backward bilinear warp, zeros padding, one frame (all B, all C).
// Block = 256 threads -> 32x32 px tile, 4 consecutive x per thread.
// Src staged per channel into LDS (64x64 fp32, double-buffered) via
// global_load_lds dwordx4; random gathers hit LDS, not L1/L2.
// Out-of-tile samples (P ~ 3.5e-4) fall back to global gather under exec mask.
__global__ __launch_bounds__(256, 4) void warp_tile_kernel(
    const float* __restrict__ src, float* __restrict__ dst,
    const float* __restrict__ flow)
{
  __shared__ float tile[2][TW * TW];   // 2 x 16 KB

  const int t  = threadIdx.x;
  const int X0 = blockIdx.x * TS;
  const int Y0 = blockIdx.y * TS;
  const int b  = blockIdx.z;

  const float* srcF = src + (long)b * FRAME_BSTRIDE;
  float*       dstF = dst + (long)b * FRAME_BSTRIDE;
  const float* fl   = flow + (long)b * FLOW_BSTRIDE;

  const int tx = (t & 7) * 4;   // 0..28 step 4
  const int ty = t >> 3;        // 0..31
  const int x  = X0 + tx;
  const int y  = Y0 + ty;
  const int pix = y * Wd + x;   // 16B-aligned (x multiple of 4)

  float4 fxv = *reinterpret_cast<const float4*>(fl + pix);
  float4 fyv = *reinterpret_cast<const float4*>(fl + HW + pix);

  // Per-pixel precompute (all j-indices compile-time via unroll -> registers).
  float w00[4], w10[4], w01[4], w11[4];
  int   lA[4];                       // LDS byte addr of corner00 (buf-relative)
  int   g00[4], g10[4], g01[4], g11[4];
  bool  ft[4];

#pragma unroll
  for (int j = 0; j < 4; ++j) {
    float fx = (j == 0) ? fxv.x : (j == 1) ? fxv.y : (j == 2) ? fxv.z : fxv.w;
    float fy = (j == 0) ? fyv.x : (j == 1) ? fyv.y : (j == 2) ? fyv.z : fyv.w;
    float gx = (float)(x + j) + fx;
    float gy = (float)y + fy;
    float x0f = floorf(gx);
    float y0f = floorf(gy);
    float wx = gx - x0f;
    float wy = gy - y0f;
    bool vx0 = (x0f >= 0.0f) && (x0f <= (float)(Wd - 1));
    bool vx1 = (x0f + 1.0f >= 0.0f) && (x0f + 1.0f <= (float)(Wd - 1));
    bool vy0 = (y0f >= 0.0f) && (y0f <= (float)(Hd - 1));
    bool vy1 = (y0f + 1.0f >= 0.0f) && (y0f + 1.0f <= (float)(Hd - 1));
    w00[j] = (1.0f - wx) * (1.0f - wy) * ((vx0 && vy0) ? 1.0f : 0.0f);
    w10[j] = wx * (1.0f - wy)          * ((vx1 && vy0) ? 1.0f : 0.0f);
    w01[j] = (1.0f - wx) * wy          * ((vx0 && vy1) ? 1.0f : 0.0f);
    w11[j] = wx * wy                   * ((vx1 && vy1) ? 1.0f : 0.0f);
    int ix0 = (int)x0f;   // exact: x0f is integer-valued
    int iy0 = (int)y0f;
    int lx = ix0 - (X0 - HALO);
    int ly = iy0 - (Y0 - HALO);
    ft[j] = (lx >= 0) & (lx <= TW - 2) & (ly >= 0) & (ly <= TW - 2);
    lA[j] = (ly * TW + lx) * 4;
    int xc0 = min(max(ix0, 0), Wd - 1);
    int xc1 = min(max(ix0 + 1, 0), Wd - 1);
    int yc0 = min(max(iy0, 0), Hd - 1);
    int yc1 = min(max(iy0 + 1, 0), Hd - 1);
    g00[j] = yc0 * Wd + xc0;
    g10[j] = yc0 * Wd + xc1;
    g01[j] = yc1 * Wd + xc0;
    g11[j] = yc1 * Wd + xc1;
  }

  // Fill plumbing: wave wv covers tile rows [wv*16, wv*16+16) via 4 GLL ops,
  // each moving 64 lanes x 16B = 4 rows. Lane l -> row +l/16, col-group l%15.
  const int lane = t & 63;
  const int wv   = t >> 6;
  const int rr   = lane >> 4;
  int gcol = X0 - HALO + (lane & 15) * 4;
  gcol = min(max(gcol, 0), Wd - 4);   // clamped groups only feed weight-0 corners

  auto fill = [&](int nb, int c) {
    const float* sC = srcF + (long)c * HW;
#pragma unroll
    for (int k = 0; k < 4; ++k) {
      int r  = wv * 16 + k * 4 + rr;
      int gr = min(max(Y0 - HALO + r, 0), Hd - 1);
      const float* gp = sC + gr * Wd + gcol;
      float* lp = &tile[nb][(wv * 16 + k * 4) * TW];
      __builtin_amdgcn_global_load_lds(
          (__attribute__((address_space(1))) void*)(void*)gp,
          (__attribute__((address_space(3))) void*)lp, 16, 0, 0);
    }
  };

  fill(0, 0);

#pragma unroll
  for (int c = 0; c < Cd; ++c) {
    __syncthreads();                         // buf[c&1] ready; prior reads done
    if (c + 1 < Cd) fill((c + 1) & 1, c + 1);  // overlaps with compute below
    const float* sC = srcF + (long)c * HW;
    const float* tb = tile[c & 1];
    float ov[4];
#pragma unroll
    for (int j = 0; j < 4; ++j) {
      float v;
      if (ft[j]) {
        const float* p = (const float*)((const char*)tb + lA[j]);
        v = w00[j] * p[0] + w10[j] * p[1] + w01[j] * p[TW] + w11[j] * p[TW + 1];
      } else {
        v = w00[j] * sC[g00[j]] + w10[j] * sC[g10[j]]
          + w01[j] * sC[g01[j]] + w11[j] * sC[g11[j]];
      }
      ov[j] = v;
    }
    float4 o;
    o.x = ov[0]; o.y = ov[1]; o.z = ov[2]; o.w = ov[3];
    *reinterpret_cast<float4*>(dstF + (long)c * HW + pix) = o;
  }
}

extern "C" void kernel_launch(void* const* d_in, const int* in_sizes, int n_in,
                              void* d_out, int out_size, void* d_ws, size_t ws_size,
                              hipStream_t stream) {
  const float* feat = (const float*)d_in[0];
  const float* mv   = (const float*)d_in[1];
  float*       out  = (float*)d_out;

  dim3 block(256, 1, 1);
  dim3 grid(Wd / TS, Hd / TS, Bd);   // 30 x 17 x 2 = 1020 blocks

  // Scratch = frame-0 slot of d_out (frame 0 is written last, by plain copy).
  float* S = out;

  auto warp = [&](const float* src, float* dst, int j) {
    warp_tile_kernel<<<grid, block, 0, stream>>>(src, dst, mv + (long)j * 2 * HW);
  };

  // frame 1: mv0
  warp(feat + 1 * CHW, out + 1 * CHW, 0);
  // frame 2: mv1, mv0  (even chain: start in scratch)
  warp(feat + 2 * CHW, S, 1);
  warp(S, out + 2 * CHW, 0);
  // frame 3: mv2, mv1, mv0  (odd chain: start in own slot)
  warp(feat + 3 * CHW, out + 3 * CHW, 2);
  warp(out + 3 * CHW, S, 1);
  warp(S, out + 3 * CHW, 0);
  // frame 4: mv3, mv2, mv1, mv0  (even chain)
  warp(feat + 4 * CHW, S, 3);
  warp(S, out + 4 * CHW, 2);
  warp(out + 4 * CHW, S, 1);
  warp(S, out + 4 * CHW, 0);

  // frame 0: plain copy (after all scratch uses of the frame-0 slot).
  for (int b = 0; b < Bd; ++b) {
    hipMemcpyAsync(out + (long)b * FRAME_BSTRIDE,
                   feat + (long)b * FRAME_BSTRIDE,
                   CHW * sizeof(float), hipMemcpyDeviceToDevice, stream);
  }
}